// Round 4
// baseline (541.796 us; speedup 1.0000x reference)
//
#include <hip/hip_runtime.h>

// LSTM(H=5, in=1), T=2048, B=8192, + ReLU + FC head.
// Round 4: 16 lanes per element -> 2048 waves = 2/SIMD (latency hiding).
// Lane s<8 owns the (i,f) gate-row pair of unit k=min(s&7,4); s>=8 owns (g,o).
// Per lane: 7 packed (v_pk_fma_f32) matvec ops; partners exchange z-pairs via
// row_shl/shr:8 DPP; both lanes redundantly run the activation (keeps exec
// uniform); h broadcast reuses Round 2's verified 9-DPP in-row scheme
// (both 8-lane halves hold identical h layouts, scheme never crosses 8-lane
// boundaries).
// Activation math (weights pre-scaled by -log2e, g-rows by -2log2e):
//   R = rcp(Ai*Ag*Af); f = Ai*Ag*R; ig = (2-Ag)*Af*R;
//   o*tanh(c) = (2-Aw)*rcp(Ao*Aw), Aw = 1+exp2(-2c*log2e)

#define TLEN 2048

typedef float v2f __attribute__((ext_vector_type(2)));

__device__ __forceinline__ float fexp2(float v) { return __builtin_amdgcn_exp2f(v); }
__device__ __forceinline__ float frcp(float v)  { return __builtin_amdgcn_rcpf(v); }
__device__ __forceinline__ v2f fma2(v2f a, v2f b, v2f c) {
    return __builtin_elementwise_fma(a, b, c);
}

template<int CTRL>
__device__ __forceinline__ float dppmov(float v) {
    return __int_as_float(__builtin_amdgcn_mov_dpp(__float_as_int(v), CTRL, 0xF, 0xF, true));
}
template<int CTRL, int BANK_MASK>
__device__ __forceinline__ float dppupd(float old, float v) {
    return __int_as_float(__builtin_amdgcn_update_dpp(
        __float_as_int(old), __float_as_int(v), CTRL, 0xF, BANK_MASK, false));
}

// Partner exchange within a 16-lane row: every lane gets lane (s^8)'s value.
// Convention (verified by R2 on HW): row_shl:n -> dst i = src i+n;
// row_shr:n -> dst i = src i-n. Banks: 0=lanes0-3,1=4-7,2=8-11,3=12-15.
__device__ __forceinline__ float xchg8(float z) {
    float t = dppupd<0x108, 0x3>(z, z);  // lanes 0-7  <- z[i+8]
    t = dppupd<0x118, 0xC>(t, z);        // lanes 8-15 <- z[i-8]
    return t;
}

__global__ __launch_bounds__(256, 2) void lstm_fused16(
    const float* __restrict__ x,      // [B, T, 1]
    const float* __restrict__ W_ih,   // [20, 1]
    const float* __restrict__ W_hh,   // [20, 5]
    const float* __restrict__ b_ih,   // [20]
    const float* __restrict__ b_hh,   // [20]
    const float* __restrict__ W_fc,   // [1, 5]
    const float* __restrict__ b_fc,   // [1]
    float* __restrict__ out, int B)
{
    const int tid = blockIdx.x * 256 + threadIdx.x;
    const int b = tid >> 4;           // batch element
    const int s = tid & 15;           // slot in 16-lane group
    const int k = (s & 7) < 5 ? (s & 7) : 4;   // owned hidden unit (dup 5-7)
    const bool low = (s < 8);         // low half = (i,f) rows, high = (g,o)

    constexpr float L2E = 1.4426950408889634f;
    const float M2L2E = -2.0f * L2E;

    // This lane's packed gate-row pair.
    const int r0 = low ? k       : 10 + k;   // i-row  or g-row
    const int r1 = low ? 5 + k   : 15 + k;   // f-row  or o-row
    const float sc0 = low ? -L2E : M2L2E;    // g-row gets -2*log2e
    const float sc1 = -L2E;

    v2f wih2, bias2, whh2[5];
    wih2  = v2f{W_ih[r0] * sc0,              W_ih[r1] * sc1};
    bias2 = v2f{(b_ih[r0] + b_hh[r0]) * sc0, (b_ih[r1] + b_hh[r1]) * sc1};
#pragma unroll
    for (int m = 0; m < 5; ++m)
        whh2[m] = v2f{W_hh[r0 * 5 + m] * sc0, W_hh[r1 * 5 + m] * sc1};

    float c = 0.0f;
    float h0v = 0.0f, h1v = 0.0f, h2v = 0.0f, h3v = 0.0f, h4v = 0.0f;

    const float4* xp = reinterpret_cast<const float4*>(x + (size_t)b * TLEN);
    float4 xv = xp[0];
#pragma unroll 1
    for (int t4 = 0; t4 < TLEN / 4; ++t4) {
        const int nxt = (t4 + 1 < TLEN / 4) ? (t4 + 1) : t4;
        float4 xn = xp[nxt];
        float xq[4] = {xv.x, xv.y, xv.z, xv.w};
#pragma unroll
        for (int q = 0; q < 4; ++q) {
            const v2f xt2 = v2f{xq[q], xq[q]};
            const v2f h0s = v2f{h0v, h0v}, h1s = v2f{h1v, h1v}, h2s = v2f{h2v, h2v};
            const v2f h3s = v2f{h3v, h3v}, h4s = v2f{h4v, h4v};

            // This lane's z pair (split-accumulated).
            v2f za = fma2(xt2, wih2, bias2);
            za = fma2(h0s, whh2[0], za);
            za = fma2(h1s, whh2[1], za);
            v2f zb = fma2(h3s, whh2[3], h2s * whh2[2]);
            zb = fma2(h4s, whh2[4], zb);
            const v2f zself = za + zb;

            // Partner's z pair.
            const v2f zoth = v2f{xchg8(zself.x), xchg8(zself.y)};

            // Role select: low half computed (zi,zf), high half (zg,zo).
            const float zi = low ? zself.x : zoth.x;
            const float zf = low ? zself.y : zoth.y;
            const float zg = low ? zoth.x  : zself.x;
            const float zo = low ? zoth.y  : zself.y;

            const float ui = fexp2(zi);   // e^{-zi}
            const float uf = fexp2(zf);   // e^{-zf}
            const float ug = fexp2(zg);   // e^{-2 zg}
            const float uo = fexp2(zo);   // e^{-zo}

            const float Ai = 1.0f + ui, Af = 1.0f + uf;
            const float Ag = 1.0f + ug, Ao = 1.0f + uo;
            const float P  = Ai * Ag;
            const float R  = frcp(P * Af);           // 1/(Ai*Ag*Af)
            const float f  = P * R;                  // sigmoid(zf)
            const float ig = (2.0f - Ag) * (Af * R); // i*g
            c = fmaf(f, c, ig);
            const float wm = fexp2(c * M2L2E);       // e^{-2c}
            const float Aw = 1.0f + wm;
            const float Ro = frcp(Ao * Aw);
            const float h  = (2.0f - Aw) * Ro;       // o*tanh(c)

            // Broadcast h[0..4] within each 8-lane half (R2 scheme, in-row).
            const float t04 = dppmov<0x00>(h);
            h0v = dppupd<0x114, 0xA>(t04, t04);
            h4v = dppupd<0x104, 0x5>(t04, t04);
            const float t1 = dppmov<0x55>(h);
            h1v = dppupd<0x114, 0xA>(t1, t1);
            const float t2 = dppmov<0xAA>(h);
            h2v = dppupd<0x114, 0xA>(t2, t2);
            const float t3 = dppmov<0xFF>(h);
            h3v = dppupd<0x114, 0xA>(t3, t3);
        }
        xv = xn;
    }

    if (s == 0) {
        float acc = b_fc[0];
        acc = fmaf(fmaxf(h0v, 0.0f), W_fc[0], acc);
        acc = fmaf(fmaxf(h1v, 0.0f), W_fc[1], acc);
        acc = fmaf(fmaxf(h2v, 0.0f), W_fc[2], acc);
        acc = fmaf(fmaxf(h3v, 0.0f), W_fc[3], acc);
        acc = fmaf(fmaxf(h4v, 0.0f), W_fc[4], acc);
        out[b] = acc;
    }
}

extern "C" void kernel_launch(void* const* d_in, const int* in_sizes, int n_in,
                              void* d_out, int out_size, void* d_ws, size_t ws_size,
                              hipStream_t stream) {
    const float* x    = (const float*)d_in[0];
    const float* W_ih = (const float*)d_in[1];
    const float* W_hh = (const float*)d_in[2];
    const float* b_ih = (const float*)d_in[3];
    const float* b_hh = (const float*)d_in[4];
    const float* W_fc = (const float*)d_in[5];
    const float* b_fc = (const float*)d_in[6];
    float* out = (float*)d_out;
    const int B = out_size;  // 8192
    const int threads = B * 16;  // 131072 = 2048 waves = 2/SIMD
    lstm_fused16<<<threads / 256, 256, 0, stream>>>(
        x, W_ih, W_hh, b_ih, b_hh, W_fc, b_fc, out, B);
}

// Round 5
// 433.358 us; speedup vs baseline: 1.2502x; 1.2502x over previous
//
#include <hip/hip_runtime.h>

// LSTM(H=5, in=1), T=2048, B=8192, + ReLU + FC head.
// Round 5: R3 structure (8 lanes/elem, 1024 waves = 1/SIMD) with the trans
// pipe mostly eliminated:
//  - all 5 exp2 -> VALU emulation (magic-const round, deg-4 Taylor, exponent
//    bits); gate exps packed in pairs.
//  - o's rcp merged into the gate rcp: R = rcp(Ai*Ag*Af*Ao), computed in
//    parallel with the c'-numerator:  c' = (P*c + (1-ug)*Af) * (R*Ao),
//    o = (P*Af)*R.  tanh(c) = 1 - 2*rcp(e^{2c}+1)  (2nd rcp).
//  Trans ops/step: 7 -> 2. DPP h-broadcast unchanged (verified since R2).
// Weights pre-scaled by -log2e (g-rows by -2log2e).

#define TLEN 2048

typedef float v2f __attribute__((ext_vector_type(2)));

__device__ __forceinline__ float frcp(float v)  { return __builtin_amdgcn_rcpf(v); }
__device__ __forceinline__ v2f fma2(v2f a, v2f b, v2f c) {
    return __builtin_elementwise_fma(a, b, c);
}

// exp2 via VALU only. Valid for |a| <= ~80 (we clamp where needed).
// bits(1.5*2^23) = 0x4B400000;  K2 = bits(C) - 127  -> scale = (bits(big)-K2)<<23
#define EXP2_C  12582912.0f
#define EXP2_K2 0x4B3FFF81
#define EC4 0.009618129f
#define EC3 0.055504109f
#define EC2 0.240226507f
#define EC1 0.693147181f

__device__ __forceinline__ float exp2_emul(float a) {
    float big = a + EXP2_C;
    float r   = a - (big - EXP2_C);
    float p = fmaf(r, EC4, EC3);
    p = fmaf(r, p, EC2);
    p = fmaf(r, p, EC1);
    p = fmaf(r, p, 1.0f);
    int sb = (__float_as_int(big) - EXP2_K2) << 23;
    return p * __int_as_float(sb);
}

__device__ __forceinline__ v2f exp2_emul2(v2f a) {
    const v2f Cv  = v2f{EXP2_C, EXP2_C};
    v2f big = a + Cv;
    v2f r   = a - (big - Cv);
    v2f p = fma2(r, v2f{EC4, EC4}, v2f{EC3, EC3});
    p = fma2(r, p, v2f{EC2, EC2});
    p = fma2(r, p, v2f{EC1, EC1});
    p = fma2(r, p, v2f{1.0f, 1.0f});
    int s0 = (__float_as_int(big.x) - EXP2_K2) << 23;
    int s1 = (__float_as_int(big.y) - EXP2_K2) << 23;
    return v2f{p.x * __int_as_float(s0), p.y * __int_as_float(s1)};
}

template<int CTRL>
__device__ __forceinline__ float dppmov(float v) {
    return __int_as_float(__builtin_amdgcn_mov_dpp(__float_as_int(v), CTRL, 0xF, 0xF, true));
}
template<int CTRL, int BANK_MASK>
__device__ __forceinline__ float dppupd(float old, float v) {
    return __int_as_float(__builtin_amdgcn_update_dpp(
        __float_as_int(old), __float_as_int(v), CTRL, 0xF, BANK_MASK, false));
}

__global__ __launch_bounds__(256, 1) void lstm_fused8e(
    const float* __restrict__ x,      // [B, T, 1]
    const float* __restrict__ W_ih,   // [20, 1]
    const float* __restrict__ W_hh,   // [20, 5]
    const float* __restrict__ b_ih,   // [20]
    const float* __restrict__ b_hh,   // [20]
    const float* __restrict__ W_fc,   // [1, 5]
    const float* __restrict__ b_fc,   // [1]
    float* __restrict__ out, int B)
{
    const int tid = blockIdx.x * 256 + threadIdx.x;
    if (tid >= B * 8) return;
    const int b = tid >> 3;
    const int lane8 = tid & 7;
    const int k = lane8 < 5 ? lane8 : 4;   // owned hidden unit (dup lanes 5-7)

    constexpr float L2E = 1.4426950408889634f;
    const float M2L2E = -2.0f * L2E;

    // Packed per-lane weights: pair01 = (i-row, f-row), pair23 = (g-row, o-row)
    v2f wih01, wih23, bias01, bias23, whh01[5], whh23[5];
    {
        const int ri = k, rf = 5 + k, rg = 10 + k, ro = 15 + k;
        wih01  = v2f{W_ih[ri] * -L2E,               W_ih[rf] * -L2E};
        wih23  = v2f{W_ih[rg] * M2L2E,              W_ih[ro] * -L2E};
        bias01 = v2f{(b_ih[ri] + b_hh[ri]) * -L2E,  (b_ih[rf] + b_hh[rf]) * -L2E};
        bias23 = v2f{(b_ih[rg] + b_hh[rg]) * M2L2E, (b_ih[ro] + b_hh[ro]) * -L2E};
#pragma unroll
        for (int m = 0; m < 5; ++m) {
            whh01[m] = v2f{W_hh[ri * 5 + m] * -L2E,  W_hh[rf * 5 + m] * -L2E};
            whh23[m] = v2f{W_hh[rg * 5 + m] * M2L2E, W_hh[ro * 5 + m] * -L2E};
        }
    }

    float c = 0.0f;
    float h0v = 0.0f, h1v = 0.0f, h2v = 0.0f, h3v = 0.0f, h4v = 0.0f;

    const float4* xp = reinterpret_cast<const float4*>(x + (size_t)b * TLEN);
    float4 xv = xp[0];
#pragma unroll 1
    for (int t4 = 0; t4 < TLEN / 4; ++t4) {
        const int nxt = (t4 + 1 < TLEN / 4) ? (t4 + 1) : t4;
        float4 xn = xp[nxt];
        float xq[4] = {xv.x, xv.y, xv.z, xv.w};
#pragma unroll
        for (int q = 0; q < 4; ++q) {
            const v2f xt2 = v2f{xq[q], xq[q]};
            const v2f h0s = v2f{h0v, h0v}, h1s = v2f{h1v, h1v}, h2s = v2f{h2v, h2v};
            const v2f h3s = v2f{h3v, h3v}, h4s = v2f{h4v, h4v};

            // z pairs (split-accumulated)
            v2f za01 = fma2(xt2, wih01, bias01);
            za01 = fma2(h0s, whh01[0], za01);
            za01 = fma2(h1s, whh01[1], za01);
            v2f zb01 = fma2(h3s, whh01[3], h2s * whh01[2]);
            zb01 = fma2(h4s, whh01[4], zb01);
            const v2f z01 = za01 + zb01;     // (zi, zf) scaled by -log2e

            v2f za23 = fma2(xt2, wih23, bias23);
            za23 = fma2(h0s, whh23[0], za23);
            za23 = fma2(h1s, whh23[1], za23);
            v2f zb23 = fma2(h3s, whh23[3], h2s * whh23[2]);
            zb23 = fma2(h4s, whh23[4], zb23);
            const v2f z23 = za23 + zb23;     // (zg*-2log2e, zo*-log2e)

            const v2f u01 = exp2_emul2(z01); // (ui, uf) = e^{-zi}, e^{-zf}
            const v2f u23 = exp2_emul2(z23); // (ug, uo) = e^{-2zg}, e^{-zo}

            const float Ai = 1.0f + u01.x, Af = 1.0f + u01.y;
            const float Ag = 1.0f + u23.x, Ao = 1.0f + u23.y;
            const float P  = Ai * Ag;
            const float D3 = P * Af;
            const float D4 = D3 * Ao;
            const float R  = frcp(D4);             // runs parallel to T below
            const float t2 = (1.0f - u23.x) * Af;  // (1-ug)*Af
            const float T  = fmaf(P, c, t2);       // numerator of c'
            const float RAo = R * Ao;
            c = T * RAo;                            // c' = f*c + i*g
            const float o  = D3 * R;                // sigmoid(zo)

            // tanh(c) = 1 - 2/(e^{2c}+1), exp via VALU emul (clamped)
            const float arg = fminf(fmaxf(c * (2.0f * L2E), -60.0f), 60.0f);
            const float E  = exp2_emul(arg);
            const float Rw = frcp(E + 1.0f);
            const float m  = o * Rw;
            const float h  = fmaf(-2.0f, m, o);     // o * tanh(c)

            // DPP broadcast of h[0..4] to all 8 lanes (verified since R2)
            const float t04 = dppmov<0x00>(h);
            h0v = dppupd<0x114, 0xA>(t04, t04);
            h4v = dppupd<0x104, 0x5>(t04, t04);
            const float t1 = dppmov<0x55>(h);
            h1v = dppupd<0x114, 0xA>(t1, t1);
            const float tt2 = dppmov<0xAA>(h);
            h2v = dppupd<0x114, 0xA>(tt2, tt2);
            const float t3 = dppmov<0xFF>(h);
            h3v = dppupd<0x114, 0xA>(t3, t3);
        }
        xv = xn;
    }

    if (lane8 == 0) {
        float acc = b_fc[0];
        acc = fmaf(fmaxf(h0v, 0.0f), W_fc[0], acc);
        acc = fmaf(fmaxf(h1v, 0.0f), W_fc[1], acc);
        acc = fmaf(fmaxf(h2v, 0.0f), W_fc[2], acc);
        acc = fmaf(fmaxf(h3v, 0.0f), W_fc[3], acc);
        acc = fmaf(fmaxf(h4v, 0.0f), W_fc[4], acc);
        out[b] = acc;
    }
}

extern "C" void kernel_launch(void* const* d_in, const int* in_sizes, int n_in,
                              void* d_out, int out_size, void* d_ws, size_t ws_size,
                              hipStream_t stream) {
    const float* x    = (const float*)d_in[0];
    const float* W_ih = (const float*)d_in[1];
    const float* W_hh = (const float*)d_in[2];
    const float* b_ih = (const float*)d_in[3];
    const float* b_hh = (const float*)d_in[4];
    const float* W_fc = (const float*)d_in[5];
    const float* b_fc = (const float*)d_in[6];
    float* out = (float*)d_out;
    const int B = out_size;  // 8192
    const int threads = B * 8;  // 65536 = 1024 waves = 1/SIMD
    lstm_fused8e<<<(threads + 255) / 256, 256, 0, stream>>>(
        x, W_ih, W_hh, b_ih, b_hh, W_fc, b_fc, out, B);
}

// Round 6
// 321.819 us; speedup vs baseline: 1.6835x; 1.3466x over previous
//
#include <hip/hip_runtime.h>

// LSTM(H=5, in=1), T=2048, B=8192, + ReLU + FC head.
// Round 6: R3 structure (8 lanes/elem, 1024 waves = 1/SIMD, hw exp2/rcp,
// packed matvec, DPP broadcast) with chain/issue polish:
//  - gate pairs re-packed as (i,g) and (f,o): P=Ai*Ag ready after the FIRST
//    exp2 pair (one exp2-latency off the critical path).
//  - scaled cell state c2 = c*(-2log2e): c2 = fmaf(f, c2, ig*M2L2E) is
//    directly the tanh exp2 argument (chain mul deleted).
//  - packed +1.0 adds for (Ai,Ag)/(Af,Ao).
//  - next-step x-base fmas (h-independent) hoisted into the rcp-latency
//    window as scheduler filler.
// Math: f = P*R, ig = (2-Ag)*Af*R, R = rcp(Ai*Ag*Af);
//       h = (2-Aw)*rcp(Ao*Aw), Aw = 1+exp2(c2).
// Weights pre-scaled by -log2e (g-rows by -2log2e).

#define TLEN 2048

typedef float v2f __attribute__((ext_vector_type(2)));

__device__ __forceinline__ float fexp2(float v) { return __builtin_amdgcn_exp2f(v); }
__device__ __forceinline__ float frcp(float v)  { return __builtin_amdgcn_rcpf(v); }
__device__ __forceinline__ v2f fma2(v2f a, v2f b, v2f c) {
    return __builtin_elementwise_fma(a, b, c);
}

template<int CTRL>
__device__ __forceinline__ float dppmov(float v) {
    return __int_as_float(__builtin_amdgcn_mov_dpp(__float_as_int(v), CTRL, 0xF, 0xF, true));
}
template<int CTRL, int BANK_MASK>
__device__ __forceinline__ float dppupd(float old, float v) {
    return __int_as_float(__builtin_amdgcn_update_dpp(
        __float_as_int(old), __float_as_int(v), CTRL, 0xF, BANK_MASK, false));
}

__global__ __launch_bounds__(256, 1) void lstm_fused8r(
    const float* __restrict__ x,      // [B, T, 1]
    const float* __restrict__ W_ih,   // [20, 1]
    const float* __restrict__ W_hh,   // [20, 5]
    const float* __restrict__ b_ih,   // [20]
    const float* __restrict__ b_hh,   // [20]
    const float* __restrict__ W_fc,   // [1, 5]
    const float* __restrict__ b_fc,   // [1]
    float* __restrict__ out, int B)
{
    const int tid = blockIdx.x * 256 + threadIdx.x;
    const int b = tid >> 3;
    const int lane8 = tid & 7;
    const int k = lane8 < 5 ? lane8 : 4;   // owned hidden unit (dup lanes 5-7)

    constexpr float L2E = 1.4426950408889634f;
    const float M2L2E = -2.0f * L2E;

    // Packed per-lane weights: pair02 = (i-row, g-row), pair13 = (f-row, o-row)
    v2f wih02, wih13, bias02, bias13, whh02[5], whh13[5];
    {
        const int ri = k, rf = 5 + k, rg = 10 + k, ro = 15 + k;
        wih02  = v2f{W_ih[ri] * -L2E,               W_ih[rg] * M2L2E};
        wih13  = v2f{W_ih[rf] * -L2E,               W_ih[ro] * -L2E};
        bias02 = v2f{(b_ih[ri] + b_hh[ri]) * -L2E,  (b_ih[rg] + b_hh[rg]) * M2L2E};
        bias13 = v2f{(b_ih[rf] + b_hh[rf]) * -L2E,  (b_ih[ro] + b_hh[ro]) * -L2E};
#pragma unroll
        for (int m = 0; m < 5; ++m) {
            whh02[m] = v2f{W_hh[ri * 5 + m] * -L2E,  W_hh[rg * 5 + m] * M2L2E};
            whh13[m] = v2f{W_hh[rf * 5 + m] * -L2E,  W_hh[ro * 5 + m] * -L2E};
        }
    }

    float c2 = 0.0f;   // scaled cell state: c * (-2*log2e)
    float h0v = 0.0f, h1v = 0.0f, h2v = 0.0f, h3v = 0.0f, h4v = 0.0f;

    const float4* xp = reinterpret_cast<const float4*>(x + (size_t)b * TLEN);
    float4 xv = xp[0];
    // x-dependent base for step 0 (h-independent part of z)
    v2f base02 = fma2(v2f{xv.x, xv.x}, wih02, bias02);
    v2f base13 = fma2(v2f{xv.x, xv.x}, wih13, bias13);

#pragma unroll 1
    for (int t4 = 0; t4 < TLEN / 4; ++t4) {
        const int nxt = (t4 + 1 < TLEN / 4) ? (t4 + 1) : t4;
        float4 xn = xp[nxt];
        float xq[4] = {xv.y, xv.z, xv.w, xn.x};  // NEXT step's x for q=0..3
#pragma unroll
        for (int q = 0; q < 4; ++q) {
            const v2f h0s = v2f{h0v, h0v}, h1s = v2f{h1v, h1v}, h2s = v2f{h2v, h2v};
            const v2f h3s = v2f{h3v, h3v}, h4s = v2f{h4v, h4v};

            // z pairs from precomputed base (split-accumulated tree)
            v2f za02 = fma2(h0s, whh02[0], base02);
            za02 = fma2(h1s, whh02[1], za02);
            v2f zb02 = fma2(h3s, whh02[3], h2s * whh02[2]);
            zb02 = fma2(h4s, whh02[4], zb02);
            const v2f z02 = za02 + zb02;         // (zi*-L2E, zg*-2L2E)

            v2f za13 = fma2(h0s, whh13[0], base13);
            za13 = fma2(h1s, whh13[1], za13);
            v2f zb13 = fma2(h3s, whh13[3], h2s * whh13[2]);
            zb13 = fma2(h4s, whh13[4], zb13);
            const v2f z13 = za13 + zb13;         // (zf*-L2E, zo*-L2E)

            const v2f u02 = v2f{fexp2(z02.x), fexp2(z02.y)};  // (ui, ug)
            const v2f u13 = v2f{fexp2(z13.x), fexp2(z13.y)};  // (uf, uo)

            const v2f A02 = u02 + v2f{1.0f, 1.0f};  // (Ai, Ag)
            const v2f A13 = u13 + v2f{1.0f, 1.0f};  // (Af, Ao)
            const float P = A02.x * A02.y;          // Ai*Ag
            const float D = P * A13.x;              // Ai*Ag*Af
            const float R = frcp(D);

            // h-independent base for the NEXT step: fills rcp/exp latency.
            const float xnx = xq[q];
            base02 = fma2(v2f{xnx, xnx}, wih02, bias02);
            base13 = fma2(v2f{xnx, xnx}, wih13, bias13);

            const float RM  = R * M2L2E;
            const float t2v = (2.0f - A02.y) * A13.x;  // (1-ug)*Af
            const float f   = P * R;                   // sigmoid(zf)
            const float igM = t2v * RM;                // (i*g)*(-2log2e)
            c2 = fmaf(f, c2, igM);                     // scaled cell state
            const float wm = fexp2(c2);                // e^{-2c}
            const float Aw = 1.0f + wm;
            const float Ro = frcp(A13.y * Aw);         // 1/(Ao*Aw)
            const float h  = (2.0f - Aw) * Ro;         // o*tanh(c)

            // DPP broadcast of h[0..4] to all 8 lanes (verified since R2)
            const float t04 = dppmov<0x00>(h);
            h0v = dppupd<0x114, 0xA>(t04, t04);
            h4v = dppupd<0x104, 0x5>(t04, t04);
            const float t1 = dppmov<0x55>(h);
            h1v = dppupd<0x114, 0xA>(t1, t1);
            const float tt2 = dppmov<0xAA>(h);
            h2v = dppupd<0x114, 0xA>(tt2, tt2);
            const float t3 = dppmov<0xFF>(h);
            h3v = dppupd<0x114, 0xA>(t3, t3);
        }
        xv = xn;
    }

    if (lane8 == 0) {
        float acc = b_fc[0];
        acc = fmaf(fmaxf(h0v, 0.0f), W_fc[0], acc);
        acc = fmaf(fmaxf(h1v, 0.0f), W_fc[1], acc);
        acc = fmaf(fmaxf(h2v, 0.0f), W_fc[2], acc);
        acc = fmaf(fmaxf(h3v, 0.0f), W_fc[3], acc);
        acc = fmaf(fmaxf(h4v, 0.0f), W_fc[4], acc);
        out[b] = acc;
    }
}

extern "C" void kernel_launch(void* const* d_in, const int* in_sizes, int n_in,
                              void* d_out, int out_size, void* d_ws, size_t ws_size,
                              hipStream_t stream) {
    const float* x    = (const float*)d_in[0];
    const float* W_ih = (const float*)d_in[1];
    const float* W_hh = (const float*)d_in[2];
    const float* b_ih = (const float*)d_in[3];
    const float* b_hh = (const float*)d_in[4];
    const float* W_fc = (const float*)d_in[5];
    const float* b_fc = (const float*)d_in[6];
    float* out = (float*)d_out;
    const int B = out_size;  // 8192
    const int threads = B * 8;  // 65536 = 1024 waves = 1/SIMD
    lstm_fused8r<<<threads / 256, 256, 0, stream>>>(
        x, W_ih, W_hh, b_ih, b_hh, W_fc, b_fc, out, B);
}

// Round 7
// 311.684 us; speedup vs baseline: 1.7383x; 1.0325x over previous
//
#include <hip/hip_runtime.h>

// LSTM(H=5, in=1), T=2048, B=8192, + ReLU + FC head.
// Round 7: R6 structure (8 lanes/elem, 1024 waves = 1/SIMD, hw exp2/rcp,
// packed matvec, DPP broadcast) with issue-count polish:
//  - fully scalar activation (no packed A-assembly -> no pack/unpack movs)
//  - (1-ug)*M2L2E folded into one fma; c2 = (P*c2 + t2vM)*R (f/RM/igM gone)
//  - h = (1-wm)*rcp(Ao*(1+wm))
//  - 8-step inner unroll (two float4 loads) halves outer-loop overhead
// Gate pairs (i,g),(f,o); weights pre-scaled by -log2e (g-rows -2log2e);
// scaled cell state c2 = c*(-2log2e) is directly the tanh exp2 argument.

#define TLEN 2048

typedef float v2f __attribute__((ext_vector_type(2)));

__device__ __forceinline__ float fexp2(float v) { return __builtin_amdgcn_exp2f(v); }
__device__ __forceinline__ float frcp(float v)  { return __builtin_amdgcn_rcpf(v); }
__device__ __forceinline__ v2f fma2(v2f a, v2f b, v2f c) {
    return __builtin_elementwise_fma(a, b, c);
}

template<int CTRL>
__device__ __forceinline__ float dppmov(float v) {
    return __int_as_float(__builtin_amdgcn_mov_dpp(__float_as_int(v), CTRL, 0xF, 0xF, true));
}
template<int CTRL, int BANK_MASK>
__device__ __forceinline__ float dppupd(float old, float v) {
    return __int_as_float(__builtin_amdgcn_update_dpp(
        __float_as_int(old), __float_as_int(v), CTRL, 0xF, BANK_MASK, false));
}

__global__ __launch_bounds__(256, 1) void lstm_fused8s(
    const float* __restrict__ x,      // [B, T, 1]
    const float* __restrict__ W_ih,   // [20, 1]
    const float* __restrict__ W_hh,   // [20, 5]
    const float* __restrict__ b_ih,   // [20]
    const float* __restrict__ b_hh,   // [20]
    const float* __restrict__ W_fc,   // [1, 5]
    const float* __restrict__ b_fc,   // [1]
    float* __restrict__ out, int B)
{
    const int tid = blockIdx.x * 256 + threadIdx.x;
    const int b = tid >> 3;
    const int lane8 = tid & 7;
    const int k = lane8 < 5 ? lane8 : 4;   // owned hidden unit (dup lanes 5-7)

    constexpr float L2E   = 1.4426950408889634f;
    constexpr float P2L2E = 2.8853900817779268f;   // +2*log2e
    constexpr float M2L2E = -2.8853900817779268f;  // -2*log2e

    // Packed per-lane weights: pair02 = (i-row, g-row), pair13 = (f-row, o-row)
    v2f wih02, wih13, bias02, bias13, whh02[5], whh13[5];
    {
        const int ri = k, rf = 5 + k, rg = 10 + k, ro = 15 + k;
        wih02  = v2f{W_ih[ri] * -L2E,               W_ih[rg] * M2L2E};
        wih13  = v2f{W_ih[rf] * -L2E,               W_ih[ro] * -L2E};
        bias02 = v2f{(b_ih[ri] + b_hh[ri]) * -L2E,  (b_ih[rg] + b_hh[rg]) * M2L2E};
        bias13 = v2f{(b_ih[rf] + b_hh[rf]) * -L2E,  (b_ih[ro] + b_hh[ro]) * -L2E};
#pragma unroll
        for (int m = 0; m < 5; ++m) {
            whh02[m] = v2f{W_hh[ri * 5 + m] * -L2E,  W_hh[rg * 5 + m] * M2L2E};
            whh13[m] = v2f{W_hh[rf * 5 + m] * -L2E,  W_hh[ro * 5 + m] * -L2E};
        }
    }

    float c2 = 0.0f;   // scaled cell state: c * (-2*log2e)
    float h0v = 0.0f, h1v = 0.0f, h2v = 0.0f, h3v = 0.0f, h4v = 0.0f;

    const float4* xp = reinterpret_cast<const float4*>(x + (size_t)b * TLEN);
    float4 xa = xp[0];
    float4 xb = xp[1];
    // h-independent base for step 0
    v2f base02 = fma2(v2f{xa.x, xa.x}, wih02, bias02);
    v2f base13 = fma2(v2f{xa.x, xa.x}, wih13, bias13);

#pragma unroll 1
    for (int t8 = 0; t8 < TLEN / 8; ++t8) {
        const int nx = (t8 + 1 < TLEN / 8) ? (t8 + 1) : t8;
        float4 na = xp[2 * nx];
        float4 nb = xp[2 * nx + 1];
        // NEXT step's x for each of the 8 steps (last is dummy on final iter)
        float xs[8] = {xa.y, xa.z, xa.w, xb.x, xb.y, xb.z, xb.w, na.x};
#pragma unroll
        for (int q = 0; q < 8; ++q) {
            const v2f h0s = v2f{h0v, h0v}, h1s = v2f{h1v, h1v}, h2s = v2f{h2v, h2v};
            const v2f h3s = v2f{h3v, h3v}, h4s = v2f{h4v, h4v};

            // z pairs from precomputed base (split-accumulated trees)
            v2f za02 = fma2(h0s, whh02[0], base02);
            za02 = fma2(h1s, whh02[1], za02);
            v2f zb02 = fma2(h3s, whh02[3], h2s * whh02[2]);
            zb02 = fma2(h4s, whh02[4], zb02);
            const v2f z02 = za02 + zb02;         // (zi*-L2E, zg*-2L2E)

            v2f za13 = fma2(h0s, whh13[0], base13);
            za13 = fma2(h1s, whh13[1], za13);
            v2f zb13 = fma2(h3s, whh13[3], h2s * whh13[2]);
            zb13 = fma2(h4s, whh13[4], zb13);
            const v2f z13 = za13 + zb13;         // (zf*-L2E, zo*-L2E)

            const float ui = fexp2(z02.x);       // e^{-zi}
            const float ug = fexp2(z02.y);       // e^{-2zg}
            const float uf = fexp2(z13.x);       // e^{-zf}
            const float uo = fexp2(z13.y);       // e^{-zo}

            const float Ai = 1.0f + ui;
            const float Ag = 1.0f + ug;
            const float Af = 1.0f + uf;
            const float Ao = 1.0f + uo;
            const float P  = Ai * Ag;
            const float D  = P * Af;
            const float R  = frcp(D);

            // h-independent base for the NEXT step: fills rcp latency.
            const float xn = xs[q];
            base02 = fma2(v2f{xn, xn}, wih02, bias02);
            base13 = fma2(v2f{xn, xn}, wih13, bias13);

            const float t2vM = fmaf(ug, P2L2E, M2L2E) * Af;  // (1-ug)*M2L2E*Af
            const float N  = fmaf(P, c2, t2vM);
            c2 = N * R;                                       // scaled cell state
            const float wm = fexp2(c2);                       // e^{-2c}
            const float Aw = 1.0f + wm;
            const float Ro = frcp(Ao * Aw);
            const float h  = (1.0f - wm) * Ro;                // o*tanh(c)

            // DPP broadcast of h[0..4] to all 8 lanes (verified since R2)
            const float t04 = dppmov<0x00>(h);
            h0v = dppupd<0x114, 0xA>(t04, t04);
            h4v = dppupd<0x104, 0x5>(t04, t04);
            const float t1 = dppmov<0x55>(h);
            h1v = dppupd<0x114, 0xA>(t1, t1);
            const float tt2 = dppmov<0xAA>(h);
            h2v = dppupd<0x114, 0xA>(tt2, tt2);
            const float t3 = dppmov<0xFF>(h);
            h3v = dppupd<0x114, 0xA>(t3, t3);
        }
        xa = na;
        xb = nb;
    }

    if (lane8 == 0) {
        float acc = b_fc[0];
        acc = fmaf(fmaxf(h0v, 0.0f), W_fc[0], acc);
        acc = fmaf(fmaxf(h1v, 0.0f), W_fc[1], acc);
        acc = fmaf(fmaxf(h2v, 0.0f), W_fc[2], acc);
        acc = fmaf(fmaxf(h3v, 0.0f), W_fc[3], acc);
        acc = fmaf(fmaxf(h4v, 0.0f), W_fc[4], acc);
        out[b] = acc;
    }
}

extern "C" void kernel_launch(void* const* d_in, const int* in_sizes, int n_in,
                              void* d_out, int out_size, void* d_ws, size_t ws_size,
                              hipStream_t stream) {
    const float* x    = (const float*)d_in[0];
    const float* W_ih = (const float*)d_in[1];
    const float* W_hh = (const float*)d_in[2];
    const float* b_ih = (const float*)d_in[3];
    const float* b_hh = (const float*)d_in[4];
    const float* W_fc = (const float*)d_in[5];
    const float* b_fc = (const float*)d_in[6];
    float* out = (float*)d_out;
    const int B = out_size;  // 8192
    const int threads = B * 8;  // 65536 = 1024 waves = 1/SIMD
    lstm_fused8s<<<threads / 256, 256, 0, stream>>>(
        x, W_ih, W_hh, b_ih, b_hh, W_fc, b_fc, out, B);
}

// Round 8
// 291.293 us; speedup vs baseline: 1.8600x; 1.0700x over previous
//
#include <hip/hip_runtime.h>

// LSTM(H=5, in=1), T=2048, B=8192, + ReLU + FC head.
// Round 8: R7 + final issue polish:
//  - fma contractions: P=(1+ui)(1+ug)=fmaf(ui,Ag,Ag); Den=Ao*(1+wm)=fmaf(Ao,wm,Ao)
//  - hazard-aware ordering: base-fmas split across the rcp-latency and
//    h->DPP hazard windows; 4 independent quad_perm movs before the 5
//    dependent row-shift updates
//  - 16-step inner unroll (four float4 loads; VGPRs free at 1 wave/SIMD)
// Structure (fixed since R6): 8 lanes/elem, 1024 waves = 1/SIMD, hw exp2/rcp,
// packed (i,g)/(f,o) matvec, scaled cell state c2=c*(-2log2e), DPP broadcast.

#define TLEN 2048

typedef float v2f __attribute__((ext_vector_type(2)));

__device__ __forceinline__ float fexp2(float v) { return __builtin_amdgcn_exp2f(v); }
__device__ __forceinline__ float frcp(float v)  { return __builtin_amdgcn_rcpf(v); }
__device__ __forceinline__ v2f fma2(v2f a, v2f b, v2f c) {
    return __builtin_elementwise_fma(a, b, c);
}

template<int CTRL>
__device__ __forceinline__ float dppmov(float v) {
    return __int_as_float(__builtin_amdgcn_mov_dpp(__float_as_int(v), CTRL, 0xF, 0xF, true));
}
template<int CTRL, int BANK_MASK>
__device__ __forceinline__ float dppupd(float old, float v) {
    return __int_as_float(__builtin_amdgcn_update_dpp(
        __float_as_int(old), __float_as_int(v), CTRL, 0xF, BANK_MASK, false));
}

__global__ __launch_bounds__(256, 1) void lstm_fused8t(
    const float* __restrict__ x,      // [B, T, 1]
    const float* __restrict__ W_ih,   // [20, 1]
    const float* __restrict__ W_hh,   // [20, 5]
    const float* __restrict__ b_ih,   // [20]
    const float* __restrict__ b_hh,   // [20]
    const float* __restrict__ W_fc,   // [1, 5]
    const float* __restrict__ b_fc,   // [1]
    float* __restrict__ out, int B)
{
    const int tid = blockIdx.x * 256 + threadIdx.x;
    const int b = tid >> 3;
    const int lane8 = tid & 7;
    const int k = lane8 < 5 ? lane8 : 4;   // owned hidden unit (dup lanes 5-7)

    constexpr float L2E   = 1.4426950408889634f;
    constexpr float P2L2E = 2.8853900817779268f;   // +2*log2e
    constexpr float M2L2E = -2.8853900817779268f;  // -2*log2e

    // Packed per-lane weights: pair02 = (i-row, g-row), pair13 = (f-row, o-row)
    v2f wih02, wih13, bias02, bias13, whh02[5], whh13[5];
    {
        const int ri = k, rf = 5 + k, rg = 10 + k, ro = 15 + k;
        wih02  = v2f{W_ih[ri] * -L2E,               W_ih[rg] * M2L2E};
        wih13  = v2f{W_ih[rf] * -L2E,               W_ih[ro] * -L2E};
        bias02 = v2f{(b_ih[ri] + b_hh[ri]) * -L2E,  (b_ih[rg] + b_hh[rg]) * M2L2E};
        bias13 = v2f{(b_ih[rf] + b_hh[rf]) * -L2E,  (b_ih[ro] + b_hh[ro]) * -L2E};
#pragma unroll
        for (int m = 0; m < 5; ++m) {
            whh02[m] = v2f{W_hh[ri * 5 + m] * -L2E,  W_hh[rg * 5 + m] * M2L2E};
            whh13[m] = v2f{W_hh[rf * 5 + m] * -L2E,  W_hh[ro * 5 + m] * -L2E};
        }
    }

    float c2 = 0.0f;   // scaled cell state: c * (-2*log2e)
    float h0v = 0.0f, h1v = 0.0f, h2v = 0.0f, h3v = 0.0f, h4v = 0.0f;

    const float4* xp = reinterpret_cast<const float4*>(x + (size_t)b * TLEN);
    float4 xa = xp[0], xb = xp[1], xc = xp[2], xd = xp[3];
    // h-independent base for step 0
    v2f base02 = fma2(v2f{xa.x, xa.x}, wih02, bias02);
    v2f base13 = fma2(v2f{xa.x, xa.x}, wih13, bias13);

#pragma unroll 1
    for (int t16 = 0; t16 < TLEN / 16; ++t16) {
        const int nx = (t16 + 1 < TLEN / 16) ? (t16 + 1) : t16;
        float4 na = xp[4 * nx];
        float4 nb = xp[4 * nx + 1];
        float4 nc = xp[4 * nx + 2];
        float4 nd = xp[4 * nx + 3];
        // NEXT step's x for each of the 16 steps (last is dummy on final iter)
        float xs[16] = {xa.y, xa.z, xa.w, xb.x, xb.y, xb.z, xb.w, xc.x,
                        xc.y, xc.z, xc.w, xd.x, xd.y, xd.z, xd.w, na.x};
#pragma unroll
        for (int q = 0; q < 16; ++q) {
            const v2f h0s = v2f{h0v, h0v}, h1s = v2f{h1v, h1v}, h2s = v2f{h2v, h2v};
            const v2f h3s = v2f{h3v, h3v}, h4s = v2f{h4v, h4v};

            // z pairs from precomputed base (split-accumulated trees)
            v2f za02 = fma2(h0s, whh02[0], base02);
            za02 = fma2(h1s, whh02[1], za02);
            v2f zb02 = fma2(h3s, whh02[3], h2s * whh02[2]);
            zb02 = fma2(h4s, whh02[4], zb02);
            const v2f z02 = za02 + zb02;         // (zi*-L2E, zg*-2L2E)

            v2f za13 = fma2(h0s, whh13[0], base13);
            za13 = fma2(h1s, whh13[1], za13);
            v2f zb13 = fma2(h3s, whh13[3], h2s * whh13[2]);
            zb13 = fma2(h4s, whh13[4], zb13);
            const v2f z13 = za13 + zb13;         // (zf*-L2E, zo*-L2E)

            const float ui = fexp2(z02.x);       // e^{-zi}
            const float ug = fexp2(z02.y);       // e^{-2zg}
            const float uf = fexp2(z13.x);       // e^{-zf}
            const float uo = fexp2(z13.y);       // e^{-zo}

            const float Ag = 1.0f + ug;
            const float Af = 1.0f + uf;
            const float Ao = 1.0f + uo;
            const float P  = fmaf(ui, Ag, Ag);   // (1+ui)(1+ug)
            const float D  = P * Af;
            const float R  = frcp(D);

            // first half of next-step base: fills rcp latency
            const float xn = xs[q];
            base02 = fma2(v2f{xn, xn}, wih02, bias02);

            const float t2vM = fmaf(ug, P2L2E, M2L2E) * Af;  // (1-ug)*M2L2E*Af
            const float N  = fmaf(P, c2, t2vM);
            c2 = N * R;                                       // scaled cell state
            const float wm = fexp2(c2);                       // e^{-2c}
            const float Den = fmaf(Ao, wm, Ao);               // Ao*(1+wm)
            const float Ro = frcp(Den);
            const float h  = (1.0f - wm) * Ro;                // o*tanh(c)

            // second half of next-step base: covers the h->DPP hazard window
            base13 = fma2(v2f{xn, xn}, wih13, bias13);

            // DPP broadcast of h[0..4]: 4 independent quad_perm movs first,
            // then the 5 dependent row-shift updates (hazard-friendly order).
            const float t04 = dppmov<0x00>(h);
            const float t1  = dppmov<0x55>(h);
            const float tt2 = dppmov<0xAA>(h);
            const float t3  = dppmov<0xFF>(h);
            h0v = dppupd<0x114, 0xA>(t04, t04);
            h4v = dppupd<0x104, 0x5>(t04, t04);
            h1v = dppupd<0x114, 0xA>(t1, t1);
            h2v = dppupd<0x114, 0xA>(tt2, tt2);
            h3v = dppupd<0x114, 0xA>(t3, t3);
        }
        xa = na; xb = nb; xc = nc; xd = nd;
    }

    if (lane8 == 0) {
        float acc = b_fc[0];
        acc = fmaf(fmaxf(h0v, 0.0f), W_fc[0], acc);
        acc = fmaf(fmaxf(h1v, 0.0f), W_fc[1], acc);
        acc = fmaf(fmaxf(h2v, 0.0f), W_fc[2], acc);
        acc = fmaf(fmaxf(h3v, 0.0f), W_fc[3], acc);
        acc = fmaf(fmaxf(h4v, 0.0f), W_fc[4], acc);
        out[b] = acc;
    }
}

extern "C" void kernel_launch(void* const* d_in, const int* in_sizes, int n_in,
                              void* d_out, int out_size, void* d_ws, size_t ws_size,
                              hipStream_t stream) {
    const float* x    = (const float*)d_in[0];
    const float* W_ih = (const float*)d_in[1];
    const float* W_hh = (const float*)d_in[2];
    const float* b_ih = (const float*)d_in[3];
    const float* b_hh = (const float*)d_in[4];
    const float* W_fc = (const float*)d_in[5];
    const float* b_fc = (const float*)d_in[6];
    float* out = (float*)d_out;
    const int B = out_size;  // 8192
    const int threads = B * 8;  // 65536 = 1024 waves = 1/SIMD
    lstm_fused8t<<<threads / 256, 256, 0, stream>>>(
        x, W_ih, W_hh, b_ih, b_hh, W_fc, b_fc, out, B);
}